// Round 1
// baseline (4075.096 us; speedup 1.0000x reference)
//
#include <hip/hip_runtime.h>

// Problem constants (from reference): bs=16, A_len=1024, P_len=2048, l=768.
// All GEMM dims are multiples of 64 (M,N) and 16 (K) -> no bounds checks.

#define TM 64
#define TN 64
#define TK 16

// Generic 64x64 tiled fp32 GEMM, 256 threads, 4x4 accum per thread.
// AMODE 0: A row-major [M,K] (lda = row stride)
// AMODE 1: A[m,k] = A0[k*lda + m]   (transposed operand, m contiguous)
// AMODE 2: virtual concat: A[m,k] = k<KH ? A0[m*KH+k]-A1[m*KH+k]
//                                        : A0[m*KH+k-KH]*A1[m*KH+k-KH]
// BT 0: B[k*ldb + n] ; BT 1: B[n*ldb + k]
template<int AMODE, int BT, int BIAS, int RELU>
__global__ __launch_bounds__(256)
void gemm64(const float* __restrict__ A0, const float* __restrict__ A1,
            const float* __restrict__ B, const float* __restrict__ bias,
            float* __restrict__ C,
            int K, int lda, int ldb, int ldc, int KH,
            long sA0, long sA1, long sB, long sC)
{
    __shared__ float As[TK][TM];
    __shared__ float Bs[TK][TN];

    const int t = threadIdx.x;
    const int z = blockIdx.z;
    A0 += (long)z * sA0;
    if constexpr (AMODE == 2) { A1 += (long)z * sA1; }
    B += (long)z * sB;
    C += (long)z * sC;

    const int m0 = blockIdx.y * TM;
    const int n0 = blockIdx.x * TN;
    const int tx = t & 15;   // n sub-tile
    const int ty = t >> 4;   // m sub-tile

    float acc[4][4] = {};

    for (int k0 = 0; k0 < K; k0 += TK) {
        // ---- load A tile into As[k][m] ----
        if constexpr (AMODE == 0) {
            const int row = t >> 2;
            const int kq  = (t & 3) * 4;
            float v[4];
            *(float4*)v = *(const float4*)(A0 + (long)(m0 + row) * lda + k0 + kq);
            As[kq + 0][row] = v[0];
            As[kq + 1][row] = v[1];
            As[kq + 2][row] = v[2];
            As[kq + 3][row] = v[3];
        } else if constexpr (AMODE == 1) {
            const int kr = t >> 4;
            const int mg = (t & 15) * 4;
            *(float4*)&As[kr][mg] = *(const float4*)(A0 + (long)(k0 + kr) * lda + m0 + mg);
        } else { // AMODE == 2 — KH divisible by TK, so the branch is tile-uniform
            const int row = t >> 2;
            const int kq  = (t & 3) * 4;
            const long base = (long)(m0 + row) * KH;
            float u[4], w[4], v[4];
            if (k0 < KH) {
                *(float4*)u = *(const float4*)(A0 + base + k0 + kq);
                *(float4*)w = *(const float4*)(A1 + base + k0 + kq);
                v[0] = u[0] - w[0]; v[1] = u[1] - w[1];
                v[2] = u[2] - w[2]; v[3] = u[3] - w[3];
            } else {
                *(float4*)u = *(const float4*)(A0 + base + (k0 - KH) + kq);
                *(float4*)w = *(const float4*)(A1 + base + (k0 - KH) + kq);
                v[0] = u[0] * w[0]; v[1] = u[1] * w[1];
                v[2] = u[2] * w[2]; v[3] = u[3] * w[3];
            }
            As[kq + 0][row] = v[0];
            As[kq + 1][row] = v[1];
            As[kq + 2][row] = v[2];
            As[kq + 3][row] = v[3];
        }

        // ---- load B tile into Bs[k][n] ----
        if constexpr (BT == 0) {
            const int kr = t >> 4;
            const int ng = (t & 15) * 4;
            *(float4*)&Bs[kr][ng] = *(const float4*)(B + (long)(k0 + kr) * ldb + n0 + ng);
        } else {
            const int nrow = t >> 2;
            const int kq   = (t & 3) * 4;
            float v[4];
            *(float4*)v = *(const float4*)(B + (long)(n0 + nrow) * ldb + k0 + kq);
            Bs[kq + 0][nrow] = v[0];
            Bs[kq + 1][nrow] = v[1];
            Bs[kq + 2][nrow] = v[2];
            Bs[kq + 3][nrow] = v[3];
        }

        __syncthreads();

        #pragma unroll
        for (int kk = 0; kk < TK; ++kk) {
            float a[4], b[4];
            *(float4*)a = *(const float4*)&As[kk][ty * 4];
            *(float4*)b = *(const float4*)&Bs[kk][tx * 4];
            #pragma unroll
            for (int i = 0; i < 4; ++i)
                #pragma unroll
                for (int j = 0; j < 4; ++j)
                    acc[i][j] += a[i] * b[j];
        }

        __syncthreads();
    }

    // ---- epilogue ----
    const int n = n0 + tx * 4;
    float bi[4] = {0.f, 0.f, 0.f, 0.f};
    if constexpr (BIAS) { *(float4*)bi = *(const float4*)&bias[n]; }
    #pragma unroll
    for (int i = 0; i < 4; ++i) {
        float o[4];
        #pragma unroll
        for (int j = 0; j < 4; ++j) {
            float v = acc[i][j] + bi[j];
            if constexpr (RELU) v = fmaxf(v, 0.f);
            o[j] = v;
        }
        *(float4*)&C[(long)(m0 + ty * 4 + i) * ldc + n] = *(float4*)o;
    }
}

// Row softmax over 1024 contiguous floats, one block (256 thr) per row, in place.
__global__ __launch_bounds__(256)
void softmax1024(float* __restrict__ W)
{
    __shared__ float red[256];
    const int t = threadIdx.x;
    float* p = W + (long)blockIdx.x * 1024;

    float v[4];
    *(float4*)v = ((const float4*)p)[t];

    float m = fmaxf(fmaxf(v[0], v[1]), fmaxf(v[2], v[3]));
    red[t] = m;
    __syncthreads();
    for (int s = 128; s > 0; s >>= 1) {
        if (t < s) red[t] = fmaxf(red[t], red[t + s]);
        __syncthreads();
    }
    m = red[0];
    __syncthreads();

    float sum = 0.f;
    #pragma unroll
    for (int j = 0; j < 4; ++j) { v[j] = __expf(v[j] - m); sum += v[j]; }
    red[t] = sum;
    __syncthreads();
    for (int s = 128; s > 0; s >>= 1) {
        if (t < s) red[t] += red[t + s];
        __syncthreads();
    }
    const float inv = 1.0f / red[0];

    #pragma unroll
    for (int j = 0; j < 4; ++j) v[j] *= inv;
    ((float4*)p)[t] = *(float4*)v;
}

extern "C" void kernel_launch(void* const* d_in, const int* in_sizes, int n_in,
                              void* d_out, int out_size, void* d_ws, size_t ws_size,
                              hipStream_t stream)
{
    const float* A     = (const float*)d_in[0]; // [16,1024,768]
    const float* P     = (const float*)d_in[1]; // [16,2048,768]
    const float* G_w   = (const float*)d_in[2]; // [768,768]
    const float* G_b   = (const float*)d_in[3]; // [768]
    const float* fca_w = (const float*)d_in[4]; // [1536,768]
    const float* fca_b = (const float*)d_in[5]; // [768]
    const float* fcp_w = (const float*)d_in[6]; // [1536,768]
    const float* fcp_b = (const float*)d_in[7]; // [768]

    const int BS = 16, AL = 1024, PL = 2048, L = 768;

    float* Ag = (float*)d_ws;                 // 16*1024*768
    float* W  = Ag + (size_t)BS * AL * L;     // 16*2048*1024
    float* MP = W  + (size_t)BS * PL * AL;    // 16*2048*768
    float* MA = MP + (size_t)BS * PL * L;     // 16*1024*768
    const size_t need = ((size_t)BS * AL * L * 2 + (size_t)BS * PL * AL
                         + (size_t)BS * PL * L) * sizeof(float); // ~336 MB
    if (ws_size < need) return; // workspace too small; nothing safe to do

    float* SA = (float*)d_out;                // 16*1024*768
    float* SP = SA + (size_t)BS * AL * L;     // 16*2048*768

    // 1. Ag = A @ G_w + G_b           (M=16384, N=768, K=768, NN + bias)
    gemm64<0, 0, 1, 0><<<dim3(L / TN, BS * AL / TM, 1), 256, 0, stream>>>(
        A, nullptr, G_w, G_b, Ag, L, L, L, L, 0, 0, 0, 0, 0);

    // 2. W = P @ Ag^T  per batch      (M=2048, N=1024, K=768, NT)
    gemm64<0, 1, 0, 0><<<dim3(AL / TN, PL / TM, BS), 256, 0, stream>>>(
        P, nullptr, Ag, nullptr, W, L, L, L, AL, 0,
        (long)PL * L, 0, (long)AL * L, (long)PL * AL);

    // 3. softmax over last dim (1024) in place
    softmax1024<<<BS * PL, 256, 0, stream>>>(W);

    // 4. MP = W @ Ag   per batch      (M=2048, N=768, K=1024, NN)
    gemm64<0, 0, 0, 0><<<dim3(L / TN, PL / TM, BS), 256, 0, stream>>>(
        W, nullptr, Ag, nullptr, MP, AL, AL, L, L, 0,
        (long)PL * AL, 0, (long)AL * L, (long)PL * L);

    // 5. MA = W^T @ P  per batch      (M=1024, N=768, K=2048, TN)
    gemm64<1, 0, 0, 0><<<dim3(L / TN, AL / TM, BS), 256, 0, stream>>>(
        W, nullptr, P, nullptr, MA, PL, AL, L, L, 0,
        (long)PL * AL, 0, (long)PL * L, (long)AL * L);

    // 6. SA = relu(concat(MA-Ag, MA*Ag) @ fca_w + fca_b)  (M=16384, K=1536)
    gemm64<2, 0, 1, 1><<<dim3(L / TN, BS * AL / TM, 1), 256, 0, stream>>>(
        MA, Ag, fca_w, fca_b, SA, 2 * L, 0, L, L, L, 0, 0, 0, 0);

    // 7. SP = relu(concat(MP-P, MP*P) @ fcp_w + fcp_b)    (M=32768, K=1536)
    gemm64<2, 0, 1, 1><<<dim3(L / TN, BS * PL / TM, 1), 256, 0, stream>>>(
        MP, P, fcp_w, fcp_b, SP, 2 * L, 0, L, L, L, 0, 0, 0, 0);
}

// Round 3
// 1068.872 us; speedup vs baseline: 3.8125x; 3.8125x over previous
//
#include <hip/hip_runtime.h>

typedef _Float16 h8 __attribute__((ext_vector_type(8)));   // 8 fp16 in 4 VGPRs
typedef _Float16 h4 __attribute__((ext_vector_type(4)));
typedef float    f4 __attribute__((ext_vector_type(4)));

// ---------------- elementwise fp32 -> fp16 convert (8 elems/thread) ----------------
__global__ __launch_bounds__(256)
void conv_f16(const float* __restrict__ in, _Float16* __restrict__ out)
{
    size_t i = ((size_t)blockIdx.x * 256 + threadIdx.x) * 8;
    float4 a = *(const float4*)(in + i);
    float4 b = *(const float4*)(in + i + 4);
    h8 o;
    o[0] = (_Float16)a.x; o[1] = (_Float16)a.y; o[2] = (_Float16)a.z; o[3] = (_Float16)a.w;
    o[4] = (_Float16)b.x; o[5] = (_Float16)b.y; o[6] = (_Float16)b.z; o[7] = (_Float16)b.w;
    *(h8*)(out + i) = o;
}

// ---------------- tiled transpose (+convert): in [R,C] -> out [C,R], fp16 out ------
template<int F32IN>
__global__ __launch_bounds__(256)
void transpose_conv(const void* __restrict__ inv, _Float16* __restrict__ out,
                    int R, int C, long sIn, long sOut)
{
    __shared__ _Float16 tile[32][33];
    const int z = blockIdx.z;
    const int c0 = blockIdx.x * 32, r0 = blockIdx.y * 32;
    const int tx = threadIdx.x & 31, ty = threadIdx.x >> 5;
    if constexpr (F32IN) {
        const float* in = (const float*)inv + (size_t)z * sIn;
        #pragma unroll
        for (int i = 0; i < 4; ++i)
            tile[ty + 8 * i][tx] = (_Float16)in[(size_t)(r0 + ty + 8 * i) * C + c0 + tx];
    } else {
        const _Float16* in = (const _Float16*)inv + (size_t)z * sIn;
        #pragma unroll
        for (int i = 0; i < 4; ++i)
            tile[ty + 8 * i][tx] = in[(size_t)(r0 + ty + 8 * i) * C + c0 + tx];
    }
    __syncthreads();
    out += (size_t)z * sOut;
    #pragma unroll
    for (int i = 0; i < 4; ++i)
        out[(size_t)(c0 + ty + 8 * i) * R + r0 + tx] = tile[tx][ty + 8 * i];
}

// ---------------- row softmax: fp32 scores [rows,1024] -> fp16 probs ---------------
__global__ __launch_bounds__(256)
void softmax1024(const float* __restrict__ S, _Float16* __restrict__ W)
{
    __shared__ float red[256];
    const int t = threadIdx.x;
    const float* p = S + (size_t)blockIdx.x * 1024;

    float v[4];
    *(float4*)v = ((const float4*)p)[t];

    float m = fmaxf(fmaxf(v[0], v[1]), fmaxf(v[2], v[3]));
    red[t] = m;
    __syncthreads();
    for (int s = 128; s > 0; s >>= 1) {
        if (t < s) red[t] = fmaxf(red[t], red[t + s]);
        __syncthreads();
    }
    m = red[0];
    __syncthreads();

    float sum = 0.f;
    #pragma unroll
    for (int j = 0; j < 4; ++j) { v[j] = __expf(v[j] - m); sum += v[j]; }
    red[t] = sum;
    __syncthreads();
    for (int s = 128; s > 0; s >>= 1) {
        if (t < s) red[t] += red[t + s];
        __syncthreads();
    }
    const float inv = 1.0f / red[0];

    h4 o;
    #pragma unroll
    for (int j = 0; j < 4; ++j) o[j] = (_Float16)(v[j] * inv);
    *(h4*)(W + (size_t)blockIdx.x * 1024 + t * 4) = o;
}

// ---------------- fp16 MFMA GEMM, TN layout --------------------------------------
// C[M,N] = A[M,K] * B[N,K]^T  (both operands K-contiguous rows)
// CONCAT: A[m,k] = k<lda ? A0[m,k]-A1[m,k] : A0[m,k-lda]*A1[m,k-lda]   (lda=KH=768)
// OUT: 0 = fp32 C ; 1 = fp16 C ; 2 = fp16 C + fp16 transposed CT (per mtb-row batch)
template<int CONCAT, int BIAS, int RELU, int OUT>
__global__ __launch_bounds__(256)
void gemm_mfma(const _Float16* __restrict__ A0, const _Float16* __restrict__ A1,
               const _Float16* __restrict__ B, const float* __restrict__ bias,
               void* __restrict__ Cv, _Float16* __restrict__ CT,
               int K, int lda, int ldb, int ldc,
               long sA, long sB, long sC,
               int mtbShift, long sCT)
{
    __shared__ _Float16 As[128][40];   // +8 pad keeps 16B-aligned frag reads
    __shared__ _Float16 Bs[128][40];

    const int t = threadIdx.x;
    const int z = blockIdx.z;
    A0 += (size_t)z * sA;
    if constexpr (CONCAT) A1 += (size_t)z * sA;
    B  += (size_t)z * sB;

    const int m0 = blockIdx.y * 128, n0 = blockIdx.x * 128;
    const int wave = t >> 6, lane = t & 63, quad = lane >> 4, lcol = lane & 15;
    const int wm = (wave >> 1) * 64, wn = (wave & 1) * 64;

    const int arow = t >> 2;            // 0..63
    const int akg  = (t & 3) * 8;       // 0,8,16,24

    f4 acc[4][4] = {};

    for (int k0 = 0; k0 < K; k0 += 32) {
        #pragma unroll
        for (int h = 0; h < 2; ++h) {
            const int row = arow + h * 64;
            // ---- A tile ----
            if constexpr (!CONCAT) {
                h8 v = *(const h8*)(A0 + (size_t)(m0 + row) * lda + k0 + akg);
                *(h8*)&As[row][akg] = v;
            } else {
                const int kk = k0 + akg;
                const bool hi = kk >= lda;          // tile-uniform: lda(=768) % 32 == 0
                const int kb = hi ? kk - lda : kk;
                h8 x = *(const h8*)(A0 + (size_t)(m0 + row) * lda + kb);
                h8 y = *(const h8*)(A1 + (size_t)(m0 + row) * lda + kb);
                h8 r;
                #pragma unroll
                for (int j = 0; j < 8; ++j)
                    r[j] = hi ? (_Float16)(x[j] * y[j]) : (_Float16)(x[j] - y[j]);
                *(h8*)&As[row][akg] = r;
            }
            // ---- B tile ----
            h8 w = *(const h8*)(B + (size_t)(n0 + row) * ldb + k0 + akg);
            *(h8*)&Bs[row][akg] = w;
        }
        __syncthreads();

        h8 af[4], bg[4];
        #pragma unroll
        for (int i = 0; i < 4; ++i) {
            af[i] = *(const h8*)&As[wm + i * 16 + lcol][quad * 8];
            bg[i] = *(const h8*)&Bs[wn + i * 16 + lcol][quad * 8];
        }
        #pragma unroll
        for (int i = 0; i < 4; ++i)
            #pragma unroll
            for (int j = 0; j < 4; ++j)
                acc[i][j] = __builtin_amdgcn_mfma_f32_16x16x32_f16(af[i], bg[j], acc[i][j], 0, 0, 0);
        __syncthreads();
    }

    // ---- epilogue: C/D layout col=lane&15, row=quad*4+reg (m89-verified) ----
    #pragma unroll
    for (int mi = 0; mi < 4; ++mi) {
        #pragma unroll
        for (int nj = 0; nj < 4; ++nj) {
            const int gm = m0 + wm + mi * 16 + quad * 4;
            const int gn = n0 + wn + nj * 16 + lcol;
            float bv = 0.f;
            if constexpr (BIAS) bv = bias[gn];
            if constexpr (OUT == 0) {
                float* C = (float*)Cv + (size_t)z * sC;
                #pragma unroll
                for (int r = 0; r < 4; ++r) {
                    float v = acc[mi][nj][r] + bv;
                    if constexpr (RELU) v = fmaxf(v, 0.f);
                    C[(size_t)(gm + r) * ldc + gn] = v;
                }
            } else {
                _Float16* C = (_Float16*)Cv + (size_t)z * sC;
                _Float16 tmp[4];
                #pragma unroll
                for (int r = 0; r < 4; ++r) {
                    float v = acc[mi][nj][r] + bv;
                    if constexpr (RELU) v = fmaxf(v, 0.f);
                    tmp[r] = (_Float16)v;
                    C[(size_t)(gm + r) * ldc + gn] = tmp[r];
                }
                if constexpr (OUT == 2) {
                    const int zz = gm >> mtbShift;
                    const int ml = gm & ((1 << mtbShift) - 1);
                    h4 o; o[0] = tmp[0]; o[1] = tmp[1]; o[2] = tmp[2]; o[3] = tmp[3];
                    *(h4*)(CT + (size_t)zz * sCT + ((size_t)gn << mtbShift) + ml) = o;
                }
            }
        }
    }
}

extern "C" void kernel_launch(void* const* d_in, const int* in_sizes, int n_in,
                              void* d_out, int out_size, void* d_ws, size_t ws_size,
                              hipStream_t stream)
{
    const float* A     = (const float*)d_in[0]; // [16,1024,768]
    const float* P     = (const float*)d_in[1]; // [16,2048,768]
    const float* G_w   = (const float*)d_in[2]; // [768,768]
    const float* G_b   = (const float*)d_in[3];
    const float* fca_w = (const float*)d_in[4]; // [1536,768]
    const float* fca_b = (const float*)d_in[5];
    const float* fcp_w = (const float*)d_in[6];
    const float* fcp_b = (const float*)d_in[7];

    const int BS = 16, AL = 1024, PL = 2048, L = 768;

    // ---- workspace layout (fp16 elements) ---------------------------------------
    _Float16* w = (_Float16*)d_ws;
    size_t off = 0;
    _Float16* P_h  = w + off; off += (size_t)BS * PL * L;   // [p,l]
    _Float16* PT_h = w + off; off += (size_t)BS * PL * L;   // [l,p] per batch
    _Float16* A_h  = w + off; off += (size_t)BS * AL * L;
    _Float16* Ag_h = w + off; off += (size_t)BS * AL * L;   // [a,l]
    _Float16* AgT  = w + off; off += (size_t)BS * AL * L;   // [l,a] per batch
    _Float16* W_h  = w + off; off += (size_t)BS * PL * AL;  // [p,a] per batch
    _Float16* MP_h = w + off; off += (size_t)BS * PL * L;
    _Float16* MA_h = w + off; off += (size_t)BS * AL * L;
    _Float16* GwT  = w + off; off += (size_t)L * L;
    _Float16* fcaT = w + off; off += (size_t)2 * L * L;
    _Float16* fcpT = w + off; off += (size_t)2 * L * L;
    if (ws_size < off * sizeof(_Float16)) return;           // ~324.7 MB

    // scores (fp32) and W^T (fp16) both live in d_out while it's otherwise dead
    float*    scores = (float*)d_out;                       // 134.2 MB of 151 MB
    _Float16* WT_h   = (_Float16*)d_out;                    // [a,p] per batch (after softmax)
    float*    SA = (float*)d_out;                           // [16,1024,768]
    float*    SP = SA + (size_t)BS * AL * L;                // [16,2048,768]

    // ---- converts & weight transposes -------------------------------------------
    conv_f16<<<(BS * AL * L) / (256 * 8), 256, 0, stream>>>(A, A_h);
    conv_f16<<<(BS * PL * L) / (256 * 8), 256, 0, stream>>>(P, P_h);
    transpose_conv<1><<<dim3(L / 32, PL / 32, BS), 256, 0, stream>>>(
        P, PT_h, PL, L, (long)PL * L, (long)PL * L);
    transpose_conv<1><<<dim3(L / 32, L / 32, 1), 256, 0, stream>>>(
        G_w, GwT, L, L, 0, 0);
    transpose_conv<1><<<dim3(L / 32, 2 * L / 32, 1), 256, 0, stream>>>(
        fca_w, fcaT, 2 * L, L, 0, 0);
    transpose_conv<1><<<dim3(L / 32, 2 * L / 32, 1), 256, 0, stream>>>(
        fcp_w, fcpT, 2 * L, L, 0, 0);

    // ---- G1: Ag = A @ G_w + G_b  -> Ag_h [a,l] and AgT [l,a]/batch ---------------
    gemm_mfma<0, 1, 0, 2><<<dim3(L / 128, BS * AL / 128, 1), 256, 0, stream>>>(
        A_h, nullptr, GwT, G_b, Ag_h, AgT,
        L, L, L, L, 0, 0, 0, 10, (long)L * AL);

    // ---- G2: scores = P @ Ag^T (per batch), fp32 out ----------------------------
    gemm_mfma<0, 0, 0, 0><<<dim3(AL / 128, PL / 128, BS), 256, 0, stream>>>(
        P_h, nullptr, Ag_h, nullptr, scores, nullptr,
        L, L, L, AL, (long)PL * L, (long)AL * L, (long)PL * AL, 0, 0);

    // ---- softmax over a (1024), fp32 -> fp16 ------------------------------------
    softmax1024<<<BS * PL, 256, 0, stream>>>(scores, W_h);

    // ---- W^T (fp16) into d_out (scores now dead) --------------------------------
    transpose_conv<0><<<dim3(AL / 32, PL / 32, BS), 256, 0, stream>>>(
        W_h, WT_h, PL, AL, (long)PL * AL, (long)PL * AL);

    // ---- G3: MP = W @ Ag (per batch) -> fp16 ------------------------------------
    gemm_mfma<0, 0, 0, 1><<<dim3(L / 128, PL / 128, BS), 256, 0, stream>>>(
        W_h, nullptr, AgT, nullptr, MP_h, nullptr,
        AL, AL, AL, L, (long)PL * AL, (long)L * AL, (long)PL * L, 0, 0);

    // ---- G4: MA = W^T @ P (per batch) -> fp16 -----------------------------------
    gemm_mfma<0, 0, 0, 1><<<dim3(L / 128, AL / 128, BS), 256, 0, stream>>>(
        WT_h, nullptr, PT_h, nullptr, MA_h, nullptr,
        PL, PL, PL, L, (long)AL * PL, (long)L * PL, (long)AL * L, 0, 0);

    // ---- G5: SA = relu(concat(MA-Ag, MA*Ag) @ fca_w + b) ------------------------
    gemm_mfma<1, 1, 1, 0><<<dim3(L / 128, BS * AL / 128, 1), 256, 0, stream>>>(
        MA_h, Ag_h, fcaT, fca_b, SA, nullptr,
        2 * L, L, 2 * L, L, 0, 0, 0, 0, 0);

    // ---- G6: SP = relu(concat(MP-P, MP*P) @ fcp_w + b) --------------------------
    gemm_mfma<1, 1, 1, 0><<<dim3(L / 128, BS * PL / 128, 1), 256, 0, stream>>>(
        MP_h, P_h, fcpT, fcp_b, SP, nullptr,
        2 * L, L, 2 * L, L, 0, 0, 0, 0, 0);
}

// Round 4
// 931.677 us; speedup vs baseline: 4.3739x; 1.1473x over previous
//
#include <hip/hip_runtime.h>

typedef _Float16 h8 __attribute__((ext_vector_type(8)));   // 8 fp16 in 4 VGPRs
typedef _Float16 h4 __attribute__((ext_vector_type(4)));
typedef float    f4 __attribute__((ext_vector_type(4)));

// async global->LDS, 16B per lane; LDS dest = wave-uniform base + lane*16
__device__ __forceinline__ void glds16(const void* g, void* l) {
    __builtin_amdgcn_global_load_lds(
        (const __attribute__((address_space(1))) unsigned*)g,
        (__attribute__((address_space(3))) unsigned*)l, 16, 0, 0);
}

// ---------------- elementwise fp32 -> fp16 convert (8 elems/thread) ----------------
__global__ __launch_bounds__(256)
void conv_f16(const float* __restrict__ in, _Float16* __restrict__ out)
{
    size_t i = ((size_t)blockIdx.x * 256 + threadIdx.x) * 8;
    float4 a = *(const float4*)(in + i);
    float4 b = *(const float4*)(in + i + 4);
    h8 o;
    o[0] = (_Float16)a.x; o[1] = (_Float16)a.y; o[2] = (_Float16)a.z; o[3] = (_Float16)a.w;
    o[4] = (_Float16)b.x; o[5] = (_Float16)b.y; o[6] = (_Float16)b.z; o[7] = (_Float16)b.w;
    *(h8*)(out + i) = o;
}

// ---------------- tiled transpose (+convert): in [R,C] -> out [C,R], fp16 out ------
template<int F32IN>
__global__ __launch_bounds__(256)
void transpose_conv(const void* __restrict__ inv, _Float16* __restrict__ out,
                    int R, int C, long sIn, long sOut)
{
    __shared__ _Float16 tile[32][33];
    const int z = blockIdx.z;
    const int c0 = blockIdx.x * 32, r0 = blockIdx.y * 32;
    const int tx = threadIdx.x & 31, ty = threadIdx.x >> 5;
    if constexpr (F32IN) {
        const float* in = (const float*)inv + (size_t)z * sIn;
        #pragma unroll
        for (int i = 0; i < 4; ++i)
            tile[ty + 8 * i][tx] = (_Float16)in[(size_t)(r0 + ty + 8 * i) * C + c0 + tx];
    } else {
        const _Float16* in = (const _Float16*)inv + (size_t)z * sIn;
        #pragma unroll
        for (int i = 0; i < 4; ++i)
            tile[ty + 8 * i][tx] = in[(size_t)(r0 + ty + 8 * i) * C + c0 + tx];
    }
    __syncthreads();
    out += (size_t)z * sOut;
    #pragma unroll
    for (int i = 0; i < 4; ++i)
        out[(size_t)(c0 + ty + 8 * i) * R + r0 + tx] = tile[tx][ty + 8 * i];
}

// ---------------- row softmax: fp32 scores [rows,1024] -> fp16 probs ---------------
__global__ __launch_bounds__(256)
void softmax1024(const float* __restrict__ S, _Float16* __restrict__ W)
{
    __shared__ float red[256];
    const int t = threadIdx.x;
    const float* p = S + (size_t)blockIdx.x * 1024;

    float v[4];
    *(float4*)v = ((const float4*)p)[t];

    float m = fmaxf(fmaxf(v[0], v[1]), fmaxf(v[2], v[3]));
    red[t] = m;
    __syncthreads();
    for (int s = 128; s > 0; s >>= 1) {
        if (t < s) red[t] = fmaxf(red[t], red[t + s]);
        __syncthreads();
    }
    m = red[0];
    __syncthreads();

    float sum = 0.f;
    #pragma unroll
    for (int j = 0; j < 4; ++j) { v[j] = __expf(v[j] - m); sum += v[j]; }
    red[t] = sum;
    __syncthreads();
    for (int s = 128; s > 0; s >>= 1) {
        if (t < s) red[t] += red[t + s];
        __syncthreads();
    }
    const float inv = 1.0f / red[0];

    h4 o;
    #pragma unroll
    for (int j = 0; j < 4; ++j) o[j] = (_Float16)(v[j] * inv);
    *(h4*)(W + (size_t)blockIdx.x * 1024 + t * 4) = o;
}

// ---------------- fp16 MFMA GEMM, TN layout, m97-style staging --------------------
// C[M,N] = A[M,K] * B[N,K]^T  (both operands K-contiguous rows)
// Tile: 128(M) x TN(N), TN = NF*32 (2x2 waves; wave = 64 x NF*16), BK=32.
// A/B staged via global_load_lds dwordx4 into unpadded LDS [row][32].
// CONCAT: A[m,k] = k<lda ? A0[m,k]-A1[m,k] : A0[m,k-lda]*A1[m,k-lda]  (lda=KH)
//         -> A staged via VGPR transform + ds_write_b128 (B still async).
// OUT: 0 = fp32 C ; 1 = fp16 C ; 2 = fp16 C + fp16 transposed CT per mtb-row batch
template<int NF, int CONCAT, int BIAS, int RELU, int OUT>
__global__ __launch_bounds__(256, 2)
void gemm_k(const _Float16* __restrict__ A0, const _Float16* __restrict__ A1,
            const _Float16* __restrict__ B, const float* __restrict__ bias,
            void* __restrict__ Cv, _Float16* __restrict__ CT,
            int K, int lda, int ldb, int ldc,
            long sA, long sB, long sC, int mtbShift, long sCT)
{
    constexpr int TN = NF * 32;
    __shared__ _Float16 As[128 * 32];   // unpadded: matches glds lane order
    __shared__ _Float16 Bs[TN * 32];

    const int t = threadIdx.x;
    const int z = blockIdx.z;
    A0 += (size_t)z * sA;
    if constexpr (CONCAT) A1 += (size_t)z * sA;
    B += (size_t)z * sB;

    const int m0 = blockIdx.y * 128, n0 = blockIdx.x * TN;
    const int wave = t >> 6, lane = t & 63, quad = lane >> 4, lcol = lane & 15;
    const int wm = (wave >> 1) * 64, wn = (wave & 1) * (NF * 16);

    const int srow = t >> 2;          // 0..63
    const int scol = (t & 3) * 8;     // 0,8,16,24
    const int wb = wave * 1024;       // this wave's 1KB chunk (bytes)

    f4 acc[4][NF] = {};

    for (int k0 = 0; k0 < K; k0 += 32) {
        // ---- stage A tile (128x32) ----
        if constexpr (!CONCAT) {
            #pragma unroll
            for (int h = 0; h < 2; ++h)
                glds16(A0 + (size_t)(m0 + srow + h * 64) * lda + k0 + scol,
                       (char*)As + h * 4096 + wb);
        } else {
            const int kk = k0 + scol;
            const bool hi = kk >= lda;          // tile-uniform: KH % 32 == 0
            const int kb = hi ? kk - lda : kk;
            #pragma unroll
            for (int h = 0; h < 2; ++h) {
                const size_t rb = (size_t)(m0 + srow + h * 64) * lda + kb;
                h8 x = *(const h8*)(A0 + rb);
                h8 y = *(const h8*)(A1 + rb);
                h8 r;
                #pragma unroll
                for (int j = 0; j < 8; ++j)
                    r[j] = hi ? (_Float16)(x[j] * y[j]) : (_Float16)(x[j] - y[j]);
                *(h8*)&As[(srow + h * 64) * 32 + scol] = r;
            }
        }
        // ---- stage B tile (TNx32) ----
        #pragma unroll
        for (int h = 0; h < TN / 64; ++h)
            glds16(B + (size_t)(n0 + srow + h * 64) * ldb + k0 + scol,
                   (char*)Bs + h * 4096 + wb);

        __syncthreads();   // compiler emits vmcnt(0) lgkmcnt(0) drain here

        h8 af[4], bg[NF];
        #pragma unroll
        for (int i = 0; i < 4; ++i)
            af[i] = *(const h8*)&As[(wm + i * 16 + lcol) * 32 + quad * 8];
        #pragma unroll
        for (int j = 0; j < NF; ++j)
            bg[j] = *(const h8*)&Bs[(wn + j * 16 + lcol) * 32 + quad * 8];
        #pragma unroll
        for (int i = 0; i < 4; ++i)
            #pragma unroll
            for (int j = 0; j < NF; ++j)
                acc[i][j] = __builtin_amdgcn_mfma_f32_16x16x32_f16(af[i], bg[j], acc[i][j], 0, 0, 0);
        __syncthreads();
    }

    // ---- epilogue: C/D layout col=lane&15, row=quad*4+reg (m89-verified) ----
    #pragma unroll
    for (int mi = 0; mi < 4; ++mi) {
        #pragma unroll
        for (int nj = 0; nj < NF; ++nj) {
            const int gm = m0 + wm + mi * 16 + quad * 4;
            const int gn = n0 + wn + nj * 16 + lcol;
            float bv = 0.f;
            if constexpr (BIAS) bv = bias[gn];
            if constexpr (OUT == 0) {
                float* C = (float*)Cv + (size_t)z * sC;
                #pragma unroll
                for (int r = 0; r < 4; ++r) {
                    float v = acc[mi][nj][r] + bv;
                    if constexpr (RELU) v = fmaxf(v, 0.f);
                    C[(size_t)(gm + r) * ldc + gn] = v;
                }
            } else {
                _Float16* C = (_Float16*)Cv + (size_t)z * sC;
                _Float16 tmp[4];
                #pragma unroll
                for (int r = 0; r < 4; ++r) {
                    float v = acc[mi][nj][r] + bv;
                    if constexpr (RELU) v = fmaxf(v, 0.f);
                    tmp[r] = (_Float16)v;
                    C[(size_t)(gm + r) * ldc + gn] = tmp[r];
                }
                if constexpr (OUT == 2) {
                    const int zz = gm >> mtbShift;
                    const int ml = gm & ((1 << mtbShift) - 1);
                    h4 o; o[0] = tmp[0]; o[1] = tmp[1]; o[2] = tmp[2]; o[3] = tmp[3];
                    *(h4*)(CT + (size_t)zz * sCT + ((size_t)gn << mtbShift) + ml) = o;
                }
            }
        }
    }
}

extern "C" void kernel_launch(void* const* d_in, const int* in_sizes, int n_in,
                              void* d_out, int out_size, void* d_ws, size_t ws_size,
                              hipStream_t stream)
{
    const float* A     = (const float*)d_in[0]; // [16,1024,768]
    const float* P     = (const float*)d_in[1]; // [16,2048,768]
    const float* G_w   = (const float*)d_in[2]; // [768,768]
    const float* G_b   = (const float*)d_in[3];
    const float* fca_w = (const float*)d_in[4]; // [1536,768]
    const float* fca_b = (const float*)d_in[5];
    const float* fcp_w = (const float*)d_in[6];
    const float* fcp_b = (const float*)d_in[7];

    const int BS = 16, AL = 1024, PL = 2048, L = 768;

    // ---- workspace layout (fp16 elements) ---------------------------------------
    _Float16* w = (_Float16*)d_ws;
    size_t off = 0;
    _Float16* P_h  = w + off; off += (size_t)BS * PL * L;   // [p,l]
    _Float16* PT_h = w + off; off += (size_t)BS * PL * L;   // [l,p] per batch
    _Float16* A_h  = w + off; off += (size_t)BS * AL * L;
    _Float16* Ag_h = w + off; off += (size_t)BS * AL * L;   // [a,l]
    _Float16* AgT  = w + off; off += (size_t)BS * AL * L;   // [l,a] per batch
    _Float16* W_h  = w + off; off += (size_t)BS * PL * AL;  // [p,a] per batch
    _Float16* MP_h = w + off; off += (size_t)BS * PL * L;
    _Float16* MA_h = w + off; off += (size_t)BS * AL * L;
    _Float16* GwT  = w + off; off += (size_t)L * L;
    _Float16* fcaT = w + off; off += (size_t)2 * L * L;
    _Float16* fcpT = w + off; off += (size_t)2 * L * L;
    if (ws_size < off * sizeof(_Float16)) return;           // ~324.7 MB

    // scores (fp32) and W^T (fp16) live in d_out while it's otherwise dead
    float*    scores = (float*)d_out;                       // 134.2 MB of 151 MB
    _Float16* WT_h   = (_Float16*)d_out;                    // [a,p] per batch (after softmax)
    float*    SA = (float*)d_out;                           // [16,1024,768]
    float*    SP = SA + (size_t)BS * AL * L;                // [16,2048,768]

    // ---- converts & weight transposes -------------------------------------------
    conv_f16<<<(BS * AL * L) / (256 * 8), 256, 0, stream>>>(A, A_h);
    conv_f16<<<(BS * PL * L) / (256 * 8), 256, 0, stream>>>(P, P_h);
    transpose_conv<1><<<dim3(L / 32, L / 32, 1), 256, 0, stream>>>(
        G_w, GwT, L, L, 0, 0);
    transpose_conv<1><<<dim3(L / 32, 2 * L / 32, 1), 256, 0, stream>>>(
        fca_w, fcaT, 2 * L, L, 0, 0);
    transpose_conv<1><<<dim3(L / 32, 2 * L / 32, 1), 256, 0, stream>>>(
        fcp_w, fcpT, 2 * L, L, 0, 0);
    // PT from fp16 P_h (halves read traffic vs fp32 P)
    transpose_conv<0><<<dim3(L / 32, PL / 32, BS), 256, 0, stream>>>(
        P_h, PT_h, PL, L, (long)PL * L, (long)PL * L);

    // ---- G1: Ag = A @ G_w + G_b  -> Ag_h [a,l] and AgT [l,a]/batch (TN=256) ------
    gemm_k<8, 0, 1, 0, 2><<<dim3(L / 256, BS * AL / 128, 1), 256, 0, stream>>>(
        A_h, nullptr, GwT, G_b, Ag_h, AgT,
        L, L, L, L, 0, 0, 0, 10, (long)L * AL);

    // ---- G2: scores = P @ Ag^T (per batch), fp32 out (TN=128) -------------------
    gemm_k<4, 0, 0, 0, 0><<<dim3(AL / 128, PL / 128, BS), 256, 0, stream>>>(
        P_h, nullptr, Ag_h, nullptr, scores, nullptr,
        L, L, L, AL, (long)PL * L, (long)AL * L, (long)PL * AL, 0, 0);

    // ---- softmax over a (1024), fp32 -> fp16 ------------------------------------
    softmax1024<<<BS * PL, 256, 0, stream>>>(scores, W_h);

    // ---- W^T (fp16) into d_out (scores now dead) --------------------------------
    transpose_conv<0><<<dim3(AL / 32, PL / 32, BS), 256, 0, stream>>>(
        W_h, WT_h, PL, AL, (long)PL * AL, (long)PL * AL);

    // ---- G3: MP = W @ Ag (per batch) -> fp16 (TN=256) ---------------------------
    gemm_k<8, 0, 0, 0, 1><<<dim3(L / 256, PL / 128, BS), 256, 0, stream>>>(
        W_h, nullptr, AgT, nullptr, MP_h, nullptr,
        AL, AL, AL, L, (long)PL * AL, (long)L * AL, (long)PL * L, 0, 0);

    // ---- G4: MA = W^T @ P (per batch) -> fp16 (TN=256) --------------------------
    gemm_k<8, 0, 0, 0, 1><<<dim3(L / 256, AL / 128, BS), 256, 0, stream>>>(
        WT_h, nullptr, PT_h, nullptr, MA_h, nullptr,
        PL, PL, PL, L, (long)AL * PL, (long)L * PL, (long)AL * L, 0, 0);

    // ---- G5: SA = relu(concat(MA-Ag, MA*Ag) @ fca_w + b) (TN=256) ---------------
    gemm_k<8, 1, 1, 1, 0><<<dim3(L / 256, BS * AL / 128, 1), 256, 0, stream>>>(
        MA_h, Ag_h, fcaT, fca_b, SA, nullptr,
        2 * L, L, 2 * L, L, 0, 0, 0, 0, 0);

    // ---- G6: SP = relu(concat(MP-P, MP*P) @ fcp_w + b) (TN=256) -----------------
    gemm_k<8, 1, 1, 1, 0><<<dim3(L / 256, BS * PL / 128, 1), 256, 0, stream>>>(
        MP_h, P_h, fcpT, fcp_b, SP, nullptr,
        2 * L, L, 2 * L, L, 0, 0, 0, 0, 0);
}